// Round 13
// baseline (143.849 us; speedup 1.0000x reference)
//
#include <hip/hip_runtime.h>

// LTPE: y(p) = x(p) - sum_j w_j * x(p + off_j), zero-padded borders,
// then instance-norm over HxW per image: (y - mean) * rsqrt(var + 4e-5).
// (The reference's out = 0.5*y + 0.5; instance norm is affine-invariant,
//  with eps folding 1e-5 -> 4e-5.)
//
// Round 13: single fused dispatch, per-image completion counters.
// Round-5's fusion failed because the spin polled with an ACQUIRE load ->
// buffer_inv (L1+L2 invalidate) PER POLL across 1024 blocks. Fix: poll
// with RELAXED atomic fetch_add(+0) (executes at the L3 coherence point,
// no cache maintenance), one acquire fence per block after spin exit.
// Grid = 1024 blocks = 4/CU (<=128 VGPR) -> all co-resident, no deadlock.
// Phase-2's initial row loads are issued BEFORE the spin to hide their
// latency under the wait.

#define HH 1024
#define WW 1024
#define HW (HH * WW)
#define NIMG 32
#define NBLK 32                  // blocks per image
#define RPB (HH / NBLK)          // 32 rows per block
#define TPB 256                  // = WW/4 float4 columns per row

typedef float vfloat4 __attribute__((ext_vector_type(4)));

// weights: j=0..7 -> 2^j/255, offsets (dy,dx):
// j0 (0,-1), j1 (1,-1), j2 (1,0), j3 (1,1), j4 (0,1), j5 (-1,1), j6 (-1,0), j7 (-1,-1)
__device__ __forceinline__ void compute_y(const float* up, const float* mid,
                                          const float* dn, float* y) {
    const float w0 = 1.f / 255.f,  w1 = 2.f / 255.f,  w2 = 4.f / 255.f,
                w3 = 8.f / 255.f,  w4 = 16.f / 255.f, w5 = 32.f / 255.f,
                w6 = 64.f / 255.f, w7 = 128.f / 255.f;
#pragma unroll
    for (int k = 0; k < 4; ++k) {
        float s = w0 * mid[k] + w4 * mid[k + 2]
                + w1 * dn[k]  + w2 * dn[k + 1] + w3 * dn[k + 2]
                + w7 * up[k]  + w6 * up[k + 1] + w5 * up[k + 2];
        y[k] = mid[k + 1] - s;
    }
}

// buf[0]=left halo, buf[1..4]=vfloat4, buf[5]=right halo; zeros out of range
__device__ __forceinline__ void load_row_g(const float* __restrict__ base,
                                           int r, int c, float* buf) {
    if (r < 0 || r >= HH) {
#pragma unroll
        for (int k = 0; k < 6; ++k) buf[k] = 0.f;
        return;
    }
    const float* row = base + (size_t)r * WW;
    const vfloat4 v = reinterpret_cast<const vfloat4*>(row)[c];
    buf[0] = (c > 0) ? row[4 * c - 1] : 0.f;
    buf[1] = v.x; buf[2] = v.y; buf[3] = v.z; buf[4] = v.w;
    buf[5] = (c < TPB - 1) ? row[4 * c + 4] : 0.f;
}

__global__ __launch_bounds__(NIMG) void ltpe_zero_counts(int* __restrict__ count) {
    count[threadIdx.x] = 0;
}

__global__ __launch_bounds__(TPB) void ltpe_fused(const float* __restrict__ x,
                                                  float* __restrict__ partials,
                                                  int* __restrict__ count,
                                                  float* __restrict__ out) {
    const int img = blockIdx.x / NBLK;
    const int blk = blockIdx.x % NBLK;
    const int c = threadIdx.x;
    const float* base = x + (size_t)img * HW;
    const int r0 = blk * RPB;

    // ---------------- phase 1: rolling-pipeline stats ----------------
    {
        float buf[4][6];
        load_row_g(base, r0 - 1, c, buf[0]);
        load_row_g(base, r0,     c, buf[1]);
        load_row_g(base, r0 + 1, c, buf[2]);
        load_row_g(base, r0 + 2, c, buf[3]);

        float s = 0.f, ss = 0.f;
#pragma unroll
        for (int i = 0; i < RPB; ++i) {
            const int r = r0 + i;
            float y[4];
            compute_y(buf[i & 3], buf[(i + 1) & 3], buf[(i + 2) & 3], y);
#pragma unroll
            for (int k = 0; k < 4; ++k) { s += y[k]; ss = fmaf(y[k], y[k], ss); }
            if (i + 2 < RPB)
                load_row_g(base, r + 3, c, buf[i & 3]);
        }

#pragma unroll
        for (int off = 32; off > 0; off >>= 1) {
            s += __shfl_down(s, off);
            ss += __shfl_down(ss, off);
        }
        __shared__ float sh[8];
        const int wave = threadIdx.x >> 6;
        const int lane = threadIdx.x & 63;
        if (lane == 0) { sh[wave] = s; sh[4 + wave] = ss; }
        __syncthreads();
        if (threadIdx.x == 0) {
            partials[img * NBLK + blk] = sh[0] + sh[1] + sh[2] + sh[3];
            partials[NIMG * NBLK + img * NBLK + blk] = sh[4] + sh[5] + sh[6] + sh[7];
            // release: wbl2 is cheap (only partials are dirty), then signal
            __hip_atomic_fetch_add(&count[img], 1, __ATOMIC_RELEASE,
                                   __HIP_MEMORY_SCOPE_AGENT);
        }
    }

    // Pre-issue phase-2's initial row loads: x data, independent of other
    // blocks; their L3 latency hides under the spin below.
    float buf[4][6];
    load_row_g(base, r0 - 1, c, buf[0]);
    load_row_g(base, r0,     c, buf[1]);
    load_row_g(base, r0 + 1, c, buf[2]);
    load_row_g(base, r0 + 2, c, buf[3]);

    // ---- wait for this image's 32 blocks; RELAXED RMW poll (no buffer_inv) ----
    if (threadIdx.x == 0) {
        while (__hip_atomic_fetch_add(&count[img], 0, __ATOMIC_RELAXED,
                                      __HIP_MEMORY_SCOPE_AGENT) < NBLK) {
            __builtin_amdgcn_s_sleep(16);
        }
    }
    __syncthreads();
    // one acquire per block: invalidate L1/L2 so partials reads are fresh
    __builtin_amdgcn_fence(__ATOMIC_ACQUIRE, "agent");

    // ------------- redundant per-block final reduce (one wave) -------------
    __shared__ float sh_stats[2];
    if (threadIdx.x < 64) {
        const int lane = threadIdx.x;
        double S = 0.0, SS = 0.0;
        if (lane < NBLK) {
            S = (double)partials[img * NBLK + lane];
            SS = (double)partials[NIMG * NBLK + img * NBLK + lane];
        }
#pragma unroll
        for (int off = 32; off > 0; off >>= 1) {
            S += __shfl_down(S, off);
            SS += __shfl_down(SS, off);
        }
        if (lane == 0) {
            const double N = (double)HW;
            const double m = S / N;
            const double var = SS / N - m * m;
            sh_stats[0] = (float)m;
            sh_stats[1] = (float)(1.0 / sqrt(var + 4e-5)); // 4*eps folds the 0.5
        }
    }
    __syncthreads();
    const float mean = sh_stats[0];
    const float scale = sh_stats[1];

    // ---------------- phase 2: normalize own rows (L3-warm) ----------------
    float* obase = out + (size_t)img * HW;
#pragma unroll
    for (int i = 0; i < RPB; ++i) {
        const int r = r0 + i;
        float y[4];
        compute_y(buf[i & 3], buf[(i + 1) & 3], buf[(i + 2) & 3], y);
        vfloat4 o;
        o.x = (y[0] - mean) * scale;
        o.y = (y[1] - mean) * scale;
        o.z = (y[2] - mean) * scale;
        o.w = (y[3] - mean) * scale;
        __builtin_nontemporal_store(
            o, reinterpret_cast<vfloat4*>(obase + (size_t)r * WW) + c);
        if (i + 2 < RPB)
            load_row_g(base, r + 3, c, buf[i & 3]);
    }
}

extern "C" void kernel_launch(void* const* d_in, const int* in_sizes, int n_in,
                              void* d_out, int out_size, void* d_ws, size_t ws_size,
                              hipStream_t stream) {
    const float* x = (const float*)d_in[0];
    float* out = (float*)d_out;
    // ws layout: [NIMG*NBLK sums][NIMG*NBLK sumsqs][NIMG counters]
    float* partials = (float*)d_ws;
    int* count = (int*)(partials + 2 * NIMG * NBLK);

    ltpe_zero_counts<<<1, NIMG, 0, stream>>>(count);
    ltpe_fused<<<NIMG * NBLK, TPB, 0, stream>>>(x, partials, count, out);
}

// Round 14
// 70.242 us; speedup vs baseline: 2.0479x; 2.0479x over previous
//
#include <hip/hip_runtime.h>

// LTPE: y(p) = x(p) - sum_j w_j * x(p + off_j), zero-padded borders,
// then instance-norm over HxW per image: (y - mean) * rsqrt(var + 4e-5).
// (The reference's out = 0.5*y + 0.5; instance norm is affine-invariant,
//  with eps folding 1e-5 -> 4e-5.)
//
// Two-kernel recompute skeleton (round-11, 69.7us best). Fusion is dead:
// three attempts (coop grid.sync 197us, acquire-poll 171us, relaxed-RMW
// poll 144us) all convoy at <23% occupancy; the split's gap is ~2us.
// Round-14 A/B: pass-2 stores PLAIN instead of nontemporal. The harness
// fill kernel sustains 7.1 TB/s with plain stores (L2 write-combining +
// lazy writeback); nt no-allocate stores measured ~3.3 TB/s here. x+out
// = 256 MB = L3 exactly, and each x line is dead after its single pass-2
// read, so losing x residency to out lines is harmless.

#define HH 1024
#define WW 1024
#define HW (HH * WW)
#define NIMG 32
#define NBLK1 64                 // pass-1 blocks per image (pure read)
#define RPB1 (HH / NBLK1)        // 16 rows per block
#define NBLK2 32                 // pass-2 blocks per image (read + store)
#define RPB2 (HH / NBLK2)        // 32 rows per block
#define TPB 256                  // = WW/4 float4 columns per row

typedef float vfloat4 __attribute__((ext_vector_type(4)));

// weights: j=0..7 -> 2^j/255, offsets (dy,dx):
// j0 (0,-1), j1 (1,-1), j2 (1,0), j3 (1,1), j4 (0,1), j5 (-1,1), j6 (-1,0), j7 (-1,-1)
__device__ __forceinline__ void compute_y(const float* up, const float* mid,
                                          const float* dn, float* y) {
    const float w0 = 1.f / 255.f,  w1 = 2.f / 255.f,  w2 = 4.f / 255.f,
                w3 = 8.f / 255.f,  w4 = 16.f / 255.f, w5 = 32.f / 255.f,
                w6 = 64.f / 255.f, w7 = 128.f / 255.f;
#pragma unroll
    for (int k = 0; k < 4; ++k) {
        float s = w0 * mid[k] + w4 * mid[k + 2]
                + w1 * dn[k]  + w2 * dn[k + 1] + w3 * dn[k + 2]
                + w7 * up[k]  + w6 * up[k + 1] + w5 * up[k + 2];
        y[k] = mid[k + 1] - s;
    }
}

// buf[0]=left halo, buf[1..4]=vfloat4, buf[5]=right halo; zeros out of range
__device__ __forceinline__ void load_row_g(const float* __restrict__ base,
                                           int r, int c, float* buf) {
    if (r < 0 || r >= HH) {
#pragma unroll
        for (int k = 0; k < 6; ++k) buf[k] = 0.f;
        return;
    }
    const float* row = base + (size_t)r * WW;
    const vfloat4 v = reinterpret_cast<const vfloat4*>(row)[c];
    buf[0] = (c > 0) ? row[4 * c - 1] : 0.f;
    buf[1] = v.x; buf[2] = v.y; buf[3] = v.z; buf[4] = v.w;
    buf[5] = (c < TPB - 1) ? row[4 * c + 4] : 0.f;
}

// ---------------- pass 1: pure-read stencil -> stats partials ----------------
__global__ __launch_bounds__(TPB) void ltpe_stats(const float* __restrict__ x,
                                                  float* __restrict__ partials) {
    const int img = blockIdx.x / NBLK1;
    const int blk = blockIdx.x % NBLK1;
    const int c = threadIdx.x;
    const float* base = x + (size_t)img * HW;
    const int r0 = blk * RPB1;

    // rolling 4-row register pipeline (2-deep prefetch), fully unrolled
    float buf[4][6];
    load_row_g(base, r0 - 1, c, buf[0]);
    load_row_g(base, r0,     c, buf[1]);
    load_row_g(base, r0 + 1, c, buf[2]);
    load_row_g(base, r0 + 2, c, buf[3]);

    float s = 0.f, ss = 0.f;
#pragma unroll
    for (int i = 0; i < RPB1; ++i) {
        const int r = r0 + i;
        float y[4];
        compute_y(buf[i & 3], buf[(i + 1) & 3], buf[(i + 2) & 3], y);
#pragma unroll
        for (int k = 0; k < 4; ++k) { s += y[k]; ss = fmaf(y[k], y[k], ss); }
        if (i + 2 < RPB1)  // row r+3 serves as dn in iter i+2
            load_row_g(base, r + 3, c, buf[i & 3]);
    }

    // block reduction: wave64 shuffle, then LDS across 4 waves
#pragma unroll
    for (int off = 32; off > 0; off >>= 1) {
        s += __shfl_down(s, off);
        ss += __shfl_down(ss, off);
    }
    __shared__ float sh[8];
    const int wave = threadIdx.x >> 6;
    const int lane = threadIdx.x & 63;
    if (lane == 0) { sh[wave] = s; sh[4 + wave] = ss; }
    __syncthreads();
    if (threadIdx.x == 0) {
        partials[img * NBLK1 + blk] = sh[0] + sh[1] + sh[2] + sh[3];
        partials[NIMG * NBLK1 + img * NBLK1 + blk] = sh[4] + sh[5] + sh[6] + sh[7];
    }
}

// ------------- pass 2: reduce head + stencil recompute + plain store -------------
__global__ __launch_bounds__(TPB) void ltpe_norm(const float* __restrict__ x,
                                                 const float* __restrict__ partials,
                                                 float* __restrict__ out) {
    const int img = blockIdx.x / NBLK2;
    const int blk = blockIdx.x % NBLK2;
    const int c = threadIdx.x;
    const float* base = x + (size_t)img * HW;
    const int r0 = blk * RPB2;

    // issue initial pipeline loads first so the reduce hides under them
    float buf[4][6];
    load_row_g(base, r0 - 1, c, buf[0]);
    load_row_g(base, r0,     c, buf[1]);
    load_row_g(base, r0 + 1, c, buf[2]);
    load_row_g(base, r0 + 2, c, buf[3]);

    // redundant per-block final reduce of this image's 64 partials (one wave)
    __shared__ float sh_stats[2];
    if (threadIdx.x < 64) {
        const int lane = threadIdx.x;
        double S = (double)partials[img * NBLK1 + lane];
        double SS = (double)partials[NIMG * NBLK1 + img * NBLK1 + lane];
#pragma unroll
        for (int off = 32; off > 0; off >>= 1) {
            S += __shfl_down(S, off);
            SS += __shfl_down(SS, off);
        }
        if (lane == 0) {
            const double N = (double)HW;
            const double m = S / N;
            const double var = SS / N - m * m;
            sh_stats[0] = (float)m;
            sh_stats[1] = (float)(1.0 / sqrt(var + 4e-5)); // 4*eps folds the 0.5
        }
    }
    __syncthreads();
    const float mean = sh_stats[0];
    const float scale = sh_stats[1];

    float* obase = out + (size_t)img * HW;

#pragma unroll
    for (int i = 0; i < RPB2; ++i) {
        const int r = r0 + i;
        float y[4];
        compute_y(buf[i & 3], buf[(i + 1) & 3], buf[(i + 2) & 3], y);
        vfloat4 o;
        o.x = (y[0] - mean) * scale;
        o.y = (y[1] - mean) * scale;
        o.z = (y[2] - mean) * scale;
        o.w = (y[3] - mean) * scale;
        // PLAIN store (A/B vs nt): L2 write-combining + lazy writeback
        reinterpret_cast<vfloat4*>(obase + (size_t)r * WW)[c] = o;
        if (i + 2 < RPB2)  // row r+3 serves as dn in iter i+2
            load_row_g(base, r + 3, c, buf[i & 3]);
    }
}

extern "C" void kernel_launch(void* const* d_in, const int* in_sizes, int n_in,
                              void* d_out, int out_size, void* d_ws, size_t ws_size,
                              hipStream_t stream) {
    const float* x = (const float*)d_in[0];
    float* out = (float*)d_out;
    float* partials = (float*)d_ws; // [NIMG*NBLK1 sums][NIMG*NBLK1 sumsqs]

    ltpe_stats<<<NIMG * NBLK1, TPB, 0, stream>>>(x, partials);
    ltpe_norm<<<NIMG * NBLK2, TPB, 0, stream>>>(x, partials, out);
}

// Round 15
// 69.789 us; speedup vs baseline: 2.0612x; 1.0065x over previous
//
#include <hip/hip_runtime.h>

// LTPE: y(p) = x(p) - sum_j w_j * x(p + off_j), zero-padded borders,
// then instance-norm over HxW per image: (y - mean) * rsqrt(var + 4e-5).
// (The reference's out = 0.5*y + 0.5; instance norm is affine-invariant,
//  with eps folding 1e-5 -> 4e-5.)
//
// Two-kernel recompute skeleton (round-11 config, 69.7us best; fusion is
// dead: 3 attempts all convoy 2-3x worse; nt-vs-plain stores = noise).
// Round-15 change: the row loader fetches the 6-float window [4c-1..4c+4]
// with exactly 2 VMEM ops -- element-unaligned dwordx4 @(4c-1) (CDNA only
// needs dword alignment) + dwordx2 @(4c+3) -- instead of 3 ops (aligned
// dwordx4 + 2 predicated scalar halo loads). Lane-0/255 edges become 6
// branchless selects (VALU is ~12% busy, free). Applied to both passes.

#define HH 1024
#define WW 1024
#define HW (HH * WW)
#define NIMG 32
#define NBLK1 64                 // pass-1 blocks per image (pure read)
#define RPB1 (HH / NBLK1)        // 16 rows per block
#define NBLK2 32                 // pass-2 blocks per image (read + nt store)
#define RPB2 (HH / NBLK2)        // 32 rows per block
#define TPB 256                  // = WW/4 float4 columns per row

typedef float vfloat4 __attribute__((ext_vector_type(4)));
typedef float vfloat4u __attribute__((ext_vector_type(4), aligned(4)));
typedef float vfloat2u __attribute__((ext_vector_type(2), aligned(4)));

// weights: j=0..7 -> 2^j/255, offsets (dy,dx):
// j0 (0,-1), j1 (1,-1), j2 (1,0), j3 (1,1), j4 (0,1), j5 (-1,1), j6 (-1,0), j7 (-1,-1)
__device__ __forceinline__ void compute_y(const float* up, const float* mid,
                                          const float* dn, float* y) {
    const float w0 = 1.f / 255.f,  w1 = 2.f / 255.f,  w2 = 4.f / 255.f,
                w3 = 8.f / 255.f,  w4 = 16.f / 255.f, w5 = 32.f / 255.f,
                w6 = 64.f / 255.f, w7 = 128.f / 255.f;
#pragma unroll
    for (int k = 0; k < 4; ++k) {
        float s = w0 * mid[k] + w4 * mid[k + 2]
                + w1 * dn[k]  + w2 * dn[k + 1] + w3 * dn[k + 2]
                + w7 * up[k]  + w6 * up[k + 1] + w5 * up[k + 2];
        y[k] = mid[k + 1] - s;
    }
}

// 6-float window [4c-1 .. 4c+4] in 2 VMEM ops; edge lanes fixed by selects.
// buf[0]=left halo, buf[1..4]=own floats, buf[5]=right halo; zeros OOB.
__device__ __forceinline__ void load_row_g(const float* __restrict__ base,
                                           int r, int c, float* buf) {
    if (r < 0 || r >= HH) {
#pragma unroll
        for (int k = 0; k < 6; ++k) buf[k] = 0.f;
        return;
    }
    const float* p = base + (size_t)r * WW + 4 * c;
    const bool notfirst = (c > 0);
    const bool notlast = (c < TPB - 1);
    // dword-aligned (4B) accesses; CDNA global loads need only dword align
    const vfloat4u a = *reinterpret_cast<const vfloat4u*>(p - (notfirst ? 1 : 0));
    const vfloat2u b = *reinterpret_cast<const vfloat2u*>(p + (notlast ? 3 : 2));
    buf[0] = notfirst ? a.x : 0.f;
    buf[1] = notfirst ? a.y : a.x;
    buf[2] = notfirst ? a.z : a.y;
    buf[3] = notfirst ? a.w : a.z;
    buf[4] = notlast ? b.x : b.y;
    buf[5] = notlast ? b.y : 0.f;
}

// ---------------- pass 1: pure-read stencil -> stats partials ----------------
__global__ __launch_bounds__(TPB) void ltpe_stats(const float* __restrict__ x,
                                                  float* __restrict__ partials) {
    const int img = blockIdx.x / NBLK1;
    const int blk = blockIdx.x % NBLK1;
    const int c = threadIdx.x;
    const float* base = x + (size_t)img * HW;
    const int r0 = blk * RPB1;

    // rolling 4-row register pipeline (2-deep prefetch), fully unrolled
    float buf[4][6];
    load_row_g(base, r0 - 1, c, buf[0]);
    load_row_g(base, r0,     c, buf[1]);
    load_row_g(base, r0 + 1, c, buf[2]);
    load_row_g(base, r0 + 2, c, buf[3]);

    float s = 0.f, ss = 0.f;
#pragma unroll
    for (int i = 0; i < RPB1; ++i) {
        const int r = r0 + i;
        float y[4];
        compute_y(buf[i & 3], buf[(i + 1) & 3], buf[(i + 2) & 3], y);
#pragma unroll
        for (int k = 0; k < 4; ++k) { s += y[k]; ss = fmaf(y[k], y[k], ss); }
        if (i + 2 < RPB1)  // row r+3 serves as dn in iter i+2
            load_row_g(base, r + 3, c, buf[i & 3]);
    }

    // block reduction: wave64 shuffle, then LDS across 4 waves
#pragma unroll
    for (int off = 32; off > 0; off >>= 1) {
        s += __shfl_down(s, off);
        ss += __shfl_down(ss, off);
    }
    __shared__ float sh[8];
    const int wave = threadIdx.x >> 6;
    const int lane = threadIdx.x & 63;
    if (lane == 0) { sh[wave] = s; sh[4 + wave] = ss; }
    __syncthreads();
    if (threadIdx.x == 0) {
        partials[img * NBLK1 + blk] = sh[0] + sh[1] + sh[2] + sh[3];
        partials[NIMG * NBLK1 + img * NBLK1 + blk] = sh[4] + sh[5] + sh[6] + sh[7];
    }
}

// ------------- pass 2: reduce head + stencil recompute + nt store -------------
__global__ __launch_bounds__(TPB) void ltpe_norm(const float* __restrict__ x,
                                                 const float* __restrict__ partials,
                                                 float* __restrict__ out) {
    const int img = blockIdx.x / NBLK2;
    const int blk = blockIdx.x % NBLK2;
    const int c = threadIdx.x;
    const float* base = x + (size_t)img * HW;
    const int r0 = blk * RPB2;

    // issue initial pipeline loads first so the reduce hides under them
    float buf[4][6];
    load_row_g(base, r0 - 1, c, buf[0]);
    load_row_g(base, r0,     c, buf[1]);
    load_row_g(base, r0 + 1, c, buf[2]);
    load_row_g(base, r0 + 2, c, buf[3]);

    // redundant per-block final reduce of this image's 64 partials (one wave)
    __shared__ float sh_stats[2];
    if (threadIdx.x < 64) {
        const int lane = threadIdx.x;
        double S = (double)partials[img * NBLK1 + lane];
        double SS = (double)partials[NIMG * NBLK1 + img * NBLK1 + lane];
#pragma unroll
        for (int off = 32; off > 0; off >>= 1) {
            S += __shfl_down(S, off);
            SS += __shfl_down(SS, off);
        }
        if (lane == 0) {
            const double N = (double)HW;
            const double m = S / N;
            const double var = SS / N - m * m;
            sh_stats[0] = (float)m;
            sh_stats[1] = (float)(1.0 / sqrt(var + 4e-5)); // 4*eps folds the 0.5
        }
    }
    __syncthreads();
    const float mean = sh_stats[0];
    const float scale = sh_stats[1];

    float* obase = out + (size_t)img * HW;

#pragma unroll
    for (int i = 0; i < RPB2; ++i) {
        const int r = r0 + i;
        float y[4];
        compute_y(buf[i & 3], buf[(i + 1) & 3], buf[(i + 2) & 3], y);
        vfloat4 o;
        o.x = (y[0] - mean) * scale;
        o.y = (y[1] - mean) * scale;
        o.z = (y[2] - mean) * scale;
        o.w = (y[3] - mean) * scale;
        // nt streaming store for the 128 MB output
        __builtin_nontemporal_store(
            o, reinterpret_cast<vfloat4*>(obase + (size_t)r * WW) + c);
        if (i + 2 < RPB2)  // row r+3 serves as dn in iter i+2
            load_row_g(base, r + 3, c, buf[i & 3]);
    }
}

extern "C" void kernel_launch(void* const* d_in, const int* in_sizes, int n_in,
                              void* d_out, int out_size, void* d_ws, size_t ws_size,
                              hipStream_t stream) {
    const float* x = (const float*)d_in[0];
    float* out = (float*)d_out;
    float* partials = (float*)d_ws; // [NIMG*NBLK1 sums][NIMG*NBLK1 sumsqs]

    ltpe_stats<<<NIMG * NBLK1, TPB, 0, stream>>>(x, partials);
    ltpe_norm<<<NIMG * NBLK2, TPB, 0, stream>>>(x, partials, out);
}